// Round 6
// baseline (6407.331 us; speedup 1.0000x reference)
//
#include <hip/hip_runtime.h>

#define N_NODES 100000
#define N_EDGES 800000
#define HDIM 100

typedef __attribute__((ext_vector_type(8))) short bf16x8;
typedef __attribute__((ext_vector_type(4))) float f32x4;

// ---------------- weight packing: W[batch][K][NC] fp32 -> transposed bf16 hi/lo [batch][NCpad][Kpad]
__global__ __launch_bounds__(256)
void pack_k(const float* __restrict__ W, ushort* __restrict__ hi, ushort* __restrict__ lo,
            int K, int NC, int Kpad, int NCpad, int total)
{
    int idx = blockIdx.x * 256 + threadIdx.x;
    if (idx >= total) return;
    int per = NCpad * Kpad;
    int b = idx / per, rem = idx - b * per;
    int col = rem / Kpad, k = rem - col * Kpad;
    float v = (col < NC && k < K) ? W[(long)b * K * NC + (long)k * NC + col] : 0.f;
    uint u = __float_as_uint(v);
    float r = v - __uint_as_float(u & 0xFFFF0000u);
    hi[idx] = (ushort)(u >> 16);
    lo[idx] = (ushort)(__float_as_uint(r) >> 16);
}

// ---------------- persistent MFMA GEMM: grid-stride tiles, double-buffered A stage, B in registers.
// TILES*16 = NCpad; TPW tiles/wave (TILES/TPW waves * 64 = 256). KS = Kpad/32 (even).
// MODE: 0 store, 1 relu, 2 C += 0.5*v. GATHER: 0 plain A; 1 cat(h[g0],h[g1],e); 2 +relu on h segs; 3 A rows via g0.
template<int TILES, int TPW, int KS, int MODE, int GATHER, int MINW>
__global__ __launch_bounds__(256, MINW)
void gemm6_k(const float* __restrict__ A,
             const ushort* __restrict__ wtH, const ushort* __restrict__ wtL,
             const float* __restrict__ bias, float* __restrict__ C,
             int M, int K, int lda, int NC, int ldc,
             const int* __restrict__ g0, const int* __restrict__ g1,
             const float* __restrict__ hbuf, const float* __restrict__ ebuf)
{
    constexpr int WAVES = TILES / TPW;
    constexpr int KPAD  = KS * 32;
    constexpr int CH    = KS / 2;           // 64-wide K chunks per tile
    static_assert(WAVES * 64 == 256, "block must be 256 threads");
    static_assert(KS % 2 == 0, "KS even");
    __shared__ ushort AsH[2][64 * 64];
    __shared__ ushort AsL[2][64 * 64];

    const int tid  = threadIdx.x;
    const int lane = tid & 63;
    const int w    = tid >> 6;
    const int ntiles = (M + 63) >> 6;
    const int ltiles = (ntiles - blockIdx.x + gridDim.x - 1) / gridDim.x;

    // ---- B fragments: load once, live across all tiles ----
    bf16x8 bH[TPW][KS], bL[TPW][KS];
#pragma unroll
    for (int tp = 0; tp < TPW; ++tp) {
        int col = (w * TPW + tp) * 16 + (lane & 15);
#pragma unroll
        for (int kk = 0; kk < KS; ++kk) {
            long o = (long)col * KPAD + kk * 32 + (lane >> 4) * 8;
            bH[tp][kk] = *(const bf16x8*)(wtH + o);
            bL[tp][kk] = *(const bf16x8*)(wtL + o);
        }
    }

    f32x4 acc[TPW][4];
#pragma unroll
    for (int tp = 0; tp < TPW; ++tp)
#pragma unroll
        for (int rg = 0; rg < 4; ++rg) acc[tp][rg] = (f32x4){0.f, 0.f, 0.f, 0.f};

    // ---- stage one 64x64 chunk (fp32 -> bf16 hi/lo, XOR-swizzled) ----
    auto stage = [&](int tl, int ch, int buf) {
        long row0 = (blockIdx.x + (long)tl * gridDim.x) * 64;
#pragma unroll
        for (int it = 0; it < 4; ++it) {
            int idx = tid + it * 256;
            int r = idx >> 4, q = idx & 15;
            long grow = row0 + r;
            int gcol = ch * 64 + q * 4;
            float4 v = make_float4(0.f, 0.f, 0.f, 0.f);
            if (GATHER == 1 || GATHER == 2) {
                if (grow < M && gcol < K) {          // seg bounds (100,200) are 4-aligned
                    int seg = (gcol >= 200) ? 2 : (gcol >= 100 ? 1 : 0);
                    int off = gcol - seg * 100;
                    long rr = (seg == 0) ? (long)g0[grow] : (seg == 1) ? (long)g1[grow] : grow;
                    const float* base = (seg == 2) ? ebuf : hbuf;
                    v = *(const float4*)&base[rr * HDIM + off];
                    if (GATHER == 2 && seg < 2) {
                        v.x = fmaxf(v.x, 0.f); v.y = fmaxf(v.y, 0.f);
                        v.z = fmaxf(v.z, 0.f); v.w = fmaxf(v.w, 0.f);
                    }
                }
            } else if (GATHER == 3) {
                if (grow < M && gcol < K) {
                    long rr = (long)g0[grow];
                    v = *(const float4*)&A[rr * (long)lda + gcol];
                }
            } else {
                if (grow < M && gcol < K)            // all K are %4==0
                    v = *(const float4*)&A[grow * (long)lda + gcol];
            }
            uint ux = __float_as_uint(v.x), uy = __float_as_uint(v.y);
            uint uz = __float_as_uint(v.z), uw = __float_as_uint(v.w);
            ushort4 hv = make_ushort4(ux >> 16, uy >> 16, uz >> 16, uw >> 16);
            float rx = v.x - __uint_as_float(ux & 0xFFFF0000u);
            float ry = v.y - __uint_as_float(uy & 0xFFFF0000u);
            float rz = v.z - __uint_as_float(uz & 0xFFFF0000u);
            float rw = v.w - __uint_as_float(uw & 0xFFFF0000u);
            ushort4 lv = make_ushort4(__float_as_uint(rx) >> 16, __float_as_uint(ry) >> 16,
                                      __float_as_uint(rz) >> 16, __float_as_uint(rw) >> 16);
            int boff = (r * 128 + q * 8) ^ ((r & 7) << 4);
            *(ushort4*)((char*)AsH[buf] + boff) = hv;
            *(ushort4*)((char*)AsL[buf] + boff) = lv;
        }
    };

    int cur = 0;
    stage(0, 0, 0);
    __syncthreads();

    for (int tl = 0; tl < ltiles; ++tl) {
#pragma unroll
        for (int ch = 0; ch < CH; ++ch) {
            // prefetch next chunk into the other buffer
            if (ch + 1 < CH)            stage(tl, ch + 1, cur ^ 1);
            else if (tl + 1 < ltiles)   stage(tl + 1, 0, cur ^ 1);
            // compute current chunk (B indices compile-time: ch, ks unrolled)
#pragma unroll
            for (int ks = 0; ks < 2; ++ks) {
#pragma unroll
                for (int rg = 0; rg < 4; ++rg) {
                    int arow = rg * 16 + (lane & 15);
                    int aoff = (arow * 128 + ks * 64 + (lane >> 4) * 16) ^ ((arow & 7) << 4);
                    bf16x8 aH = *(const bf16x8*)((const char*)AsH[cur] + aoff);
                    bf16x8 aL = *(const bf16x8*)((const char*)AsL[cur] + aoff);
#pragma unroll
                    for (int tp = 0; tp < TPW; ++tp) {
                        acc[tp][rg] = __builtin_amdgcn_mfma_f32_16x16x32_bf16(aH, bH[tp][ch * 2 + ks], acc[tp][rg], 0, 0, 0);
                        acc[tp][rg] = __builtin_amdgcn_mfma_f32_16x16x32_bf16(aH, bL[tp][ch * 2 + ks], acc[tp][rg], 0, 0, 0);
                        acc[tp][rg] = __builtin_amdgcn_mfma_f32_16x16x32_bf16(aL, bH[tp][ch * 2 + ks], acc[tp][rg], 0, 0, 0);
                    }
                }
            }
            if (ch == CH - 1) {
                // epilogue for this tile; C/D layout col=lane&15, row=(lane>>4)*4+i
                long row0 = (blockIdx.x + (long)tl * gridDim.x) * 64;
#pragma unroll
                for (int tp = 0; tp < TPW; ++tp) {
                    int col = (w * TPW + tp) * 16 + (lane & 15);
                    if (col < NC) {
                        float bv = bias[col];
#pragma unroll
                        for (int rg = 0; rg < 4; ++rg) {
#pragma unroll
                            for (int i = 0; i < 4; ++i) {
                                long grow = row0 + rg * 16 + (lane >> 4) * 4 + i;
                                if (grow >= M) continue;
                                float v = acc[tp][rg][i] + bv;
                                if (MODE == 1) v = fmaxf(v, 0.f);
                                long o = grow * (long)ldc + col;
                                if (MODE == 2) C[o] += 0.5f * v;
                                else           C[o] = v;
                            }
                        }
                    }
#pragma unroll
                    for (int rg = 0; rg < 4; ++rg) acc[tp][rg] = (f32x4){0.f, 0.f, 0.f, 0.f};
                }
            }
            __syncthreads();
            cur ^= 1;
        }
    }
}

// ---------------- fused final: out = relu(f1 @ mw2 + mb2) @ mw3 + mb3, scattered to original edge order
__global__ __launch_bounds__(256, 3)
void final_fused_k(const float* __restrict__ f1,   // [E][52] permuted, cols 50-51 garbage
                   const ushort* __restrict__ m2H, const ushort* __restrict__ m2L, // NCpad=32, Kpad=64
                   const float* __restrict__ mb2, const float* __restrict__ mw3,
                   const float* __restrict__ mb3,
                   const int* __restrict__ eidx, float* __restrict__ out)
{
    __shared__ ushort AsH[2][64 * 64];
    __shared__ ushort AsL[2][64 * 64];
    const int tid = threadIdx.x, lane = tid & 63, w = tid >> 6;
    const int c = lane & 15;
    const int ntiles = N_EDGES / 64;
    const int ltiles = (ntiles - blockIdx.x + gridDim.x - 1) / gridDim.x;

    bf16x8 bH[2][2], bL[2][2];
#pragma unroll
    for (int t = 0; t < 2; ++t)
#pragma unroll
        for (int ks = 0; ks < 2; ++ks) {
            long o = (long)(t * 16 + c) * 64 + ks * 32 + (lane >> 4) * 8;
            bH[t][ks] = *(const bf16x8*)(m2H + o);
            bL[t][ks] = *(const bf16x8*)(m2L + o);
        }
    const float bias0 = mb2[c];
    const float bias1 = (c + 16 < 25) ? mb2[c + 16] : 0.f;
    const float w3a0 = mw3[c * 2 + 0], w3a1 = mw3[c * 2 + 1];
    const float w3b0 = (c + 16 < 25) ? mw3[(c + 16) * 2 + 0] : 0.f;
    const float w3b1 = (c + 16 < 25) ? mw3[(c + 16) * 2 + 1] : 0.f;
    const float b30 = mb3[0], b31 = mb3[1];

    auto stage = [&](int tl, int buf) {
        long row0 = (blockIdx.x + (long)tl * gridDim.x) * 64;
#pragma unroll
        for (int it = 0; it < 4; ++it) {
            int idx = tid + it * 256;
            int r = idx >> 4, q = idx & 15;
            long grow = row0 + r;
            float4 v = make_float4(0.f, 0.f, 0.f, 0.f);
            if (q < 13) {
                v = *(const float4*)&f1[grow * 52 + q * 4];
                if (q == 12) { v.z = 0.f; v.w = 0.f; }   // cols 50,51 garbage
            }
            uint ux = __float_as_uint(v.x), uy = __float_as_uint(v.y);
            uint uz = __float_as_uint(v.z), uw = __float_as_uint(v.w);
            ushort4 hv = make_ushort4(ux >> 16, uy >> 16, uz >> 16, uw >> 16);
            float rx = v.x - __uint_as_float(ux & 0xFFFF0000u);
            float ry = v.y - __uint_as_float(uy & 0xFFFF0000u);
            float rz = v.z - __uint_as_float(uz & 0xFFFF0000u);
            float rw = v.w - __uint_as_float(uw & 0xFFFF0000u);
            ushort4 lv = make_ushort4(__float_as_uint(rx) >> 16, __float_as_uint(ry) >> 16,
                                      __float_as_uint(rz) >> 16, __float_as_uint(rw) >> 16);
            int boff = (r * 128 + q * 8) ^ ((r & 7) << 4);
            *(ushort4*)((char*)AsH[buf] + boff) = hv;
            *(ushort4*)((char*)AsL[buf] + boff) = lv;
        }
    };

    int cur = 0;
    stage(0, 0);
    __syncthreads();
    for (int tl = 0; tl < ltiles; ++tl) {
        if (tl + 1 < ltiles) stage(tl + 1, cur ^ 1);
        f32x4 a0 = (f32x4){0.f, 0.f, 0.f, 0.f}, a1 = a0;
        const int arow = w * 16 + c;
#pragma unroll
        for (int ks = 0; ks < 2; ++ks) {
            int aoff = (arow * 128 + ks * 64 + (lane >> 4) * 16) ^ ((arow & 7) << 4);
            bf16x8 aH = *(const bf16x8*)((const char*)AsH[cur] + aoff);
            bf16x8 aL = *(const bf16x8*)((const char*)AsL[cur] + aoff);
            a0 = __builtin_amdgcn_mfma_f32_16x16x32_bf16(aH, bH[0][ks], a0, 0, 0, 0);
            a0 = __builtin_amdgcn_mfma_f32_16x16x32_bf16(aH, bL[0][ks], a0, 0, 0, 0);
            a0 = __builtin_amdgcn_mfma_f32_16x16x32_bf16(aL, bH[0][ks], a0, 0, 0, 0);
            a1 = __builtin_amdgcn_mfma_f32_16x16x32_bf16(aH, bH[1][ks], a1, 0, 0, 0);
            a1 = __builtin_amdgcn_mfma_f32_16x16x32_bf16(aH, bL[1][ks], a1, 0, 0, 0);
            a1 = __builtin_amdgcn_mfma_f32_16x16x32_bf16(aL, bH[1][ks], a1, 0, 0, 0);
        }
        long row0 = (blockIdx.x + (long)tl * gridDim.x) * 64;
#pragma unroll
        for (int i = 0; i < 4; ++i) {
            float t0 = fmaxf(a0[i] + bias0, 0.f);
            float t1 = fmaxf(a1[i] + bias1, 0.f);
            float s0 = t0 * w3a0 + t1 * w3b0;
            float s1 = t0 * w3a1 + t1 * w3b1;
#pragma unroll
            for (int d = 1; d < 16; d <<= 1) {
                s0 += __shfl_xor(s0, d, 64);
                s1 += __shfl_xor(s1, d, 64);
            }
            if (c == 0) {
                long grow = row0 + w * 16 + (lane >> 4) * 4 + i;
                int oe = eidx[grow];
                out[(long)oe * 2 + 0] = s0 + b30;
                out[(long)oe * 2 + 1] = s1 + b31;
            }
        }
        __syncthreads();
        cur ^= 1;
    }
}

// ---------------- CSR build ----------------
__global__ __launch_bounds__(256)
void hist_k(const int* __restrict__ dst, int* __restrict__ cnt)
{
    int e = blockIdx.x * 256 + threadIdx.x;
    if (e < N_EDGES) atomicAdd(&cnt[dst[e]], 1);
}

__global__ __launch_bounds__(1024)
void scan_k(const int* __restrict__ cnt, int* __restrict__ off)
{
    __shared__ int part[1024];
    const int t = threadIdx.x;
    const int per = (N_NODES + 1023) / 1024;
    const int base = t * per;
    int s = 0;
    for (int i = 0; i < per; ++i) {
        int n = base + i;
        if (n < N_NODES) s += cnt[n];
    }
    part[t] = s;
    __syncthreads();
    for (int d = 1; d < 1024; d <<= 1) {
        int v = (t >= d) ? part[t - d] : 0;
        __syncthreads();
        part[t] += v;
        __syncthreads();
    }
    int run = (t == 0) ? 0 : part[t - 1];
    for (int i = 0; i < per; ++i) {
        int n = base + i;
        if (n < N_NODES) { off[n] = run; run += cnt[n]; }
    }
    if (t == 1023) off[N_NODES] = run;
}

__global__ __launch_bounds__(256)
void fill_k(const int* __restrict__ dst, const int* __restrict__ off,
            int* __restrict__ pos, int* __restrict__ eidx)
{
    int e = blockIdx.x * 256 + threadIdx.x;
    if (e >= N_EDGES) return;
    int d = dst[e];
    int p = atomicAdd(&pos[d], 1);
    eidx[off[d] + p] = e;
}

__global__ __launch_bounds__(256)
void perm_k(const int* __restrict__ eidx, const int* __restrict__ src,
            const int* __restrict__ dst, int* __restrict__ psrc, int* __restrict__ pdst)
{
    int j = blockIdx.x * 256 + threadIdx.x;
    if (j >= N_EDGES) return;
    int e = eidx[j];
    psrc[j] = src[e];
    pdst[j] = dst[e];
}

// ---------------- aggregation (CSR-sequential): agg[n] = h[n] + sum_j relu(h[psrc[j]] + tmp[j])
__global__ __launch_bounds__(256)
void agg_k(const float* __restrict__ h, const float* __restrict__ tmp,
           const int* __restrict__ psrc, const int* __restrict__ off,
           float* __restrict__ agg)
{
    unsigned idx = blockIdx.x * 256u + threadIdx.x;
    if (idx >= (unsigned)(N_NODES * 25)) return;
    unsigned n = idx / 25u;
    unsigned q = (idx - n * 25u) * 4u;
    float4 a = *(const float4*)&h[(long)n * HDIM + q];
    int j0 = off[n], j1 = off[n + 1];
    for (int j = j0; j < j1; ++j) {
        int s = psrc[j];
        float4 t  = *(const float4*)&tmp[(long)j * HDIM + q];
        float4 hv = *(const float4*)&h[(long)s * HDIM + q];
        a.x += fmaxf(hv.x + t.x, 0.f);
        a.y += fmaxf(hv.y + t.y, 0.f);
        a.z += fmaxf(hv.z + t.z, 0.f);
        a.w += fmaxf(hv.w + t.w, 0.f);
    }
    *(float4*)&agg[(long)n * HDIM + q] = a;
}

__global__ __launch_bounds__(128)
void bn_stats_k(const float* __restrict__ z, float* __restrict__ stats)
{
    int c = threadIdx.x;
    if (c >= HDIM) return;
    long rows_per = (N_NODES + gridDim.x - 1) / gridDim.x;
    long r0 = (long)blockIdx.x * rows_per;
    long r1 = r0 + rows_per; if (r1 > N_NODES) r1 = N_NODES;
    float s = 0.f, s2 = 0.f;
    for (long r = r0; r < r1; ++r) {
        float v = z[r * HDIM + c];
        s += v; s2 += v * v;
    }
    atomicAdd(&stats[c], s);
    atomicAdd(&stats[HDIM + c], s2);
}

__global__ __launch_bounds__(256)
void bn_apply_k(const float* __restrict__ z, const float* __restrict__ stats,
                const float* __restrict__ gamma, const float* __restrict__ beta,
                float* __restrict__ h)
{
    unsigned idx = blockIdx.x * 256u + threadIdx.x;
    if (idx >= (unsigned)(N_NODES * HDIM)) return;
    unsigned c = idx % HDIM;
    const float invN = 1.f / N_NODES;
    float mu  = stats[c] * invN;
    float var = stats[HDIM + c] * invN - mu * mu;
    float v = (z[idx] - mu) * rsqrtf(var + 1e-5f) * gamma[c] + beta[c];
    h[idx] = (h[idx] + fmaxf(v, 0.f)) * 0.5f;
}

static inline int gtile(long m) { int nt = (int)((m + 63) / 64); return nt < 1024 ? nt : 1024; }

extern "C" void kernel_launch(void* const* d_in, const int* in_sizes, int n_in,
                              void* d_out, int out_size, void* d_ws, size_t ws_size,
                              hipStream_t stream)
{
    const float* x         = (const float*)d_in[0];
    const int*   ei        = (const int*)  d_in[1];
    const float* edge_attr = (const float*)d_in[2];
    const float* node_w    = (const float*)d_in[3];
    const float* node_b    = (const float*)d_in[4];
    const float* edge_w    = (const float*)d_in[5];
    const float* edge_b    = (const float*)d_in[6];
    const float* lin_w     = (const float*)d_in[7];
    const float* lin_b     = (const float*)d_in[8];
    const float* w1        = (const float*)d_in[9];
    const float* b1        = (const float*)d_in[10];
    const float* w2        = (const float*)d_in[11];
    const float* b2        = (const float*)d_in[12];
    const float* gamma     = (const float*)d_in[13];
    const float* beta      = (const float*)d_in[14];
    const float* ew1       = (const float*)d_in[15];
    const float* eb1       = (const float*)d_in[16];
    const float* ew2       = (const float*)d_in[17];
    const float* eb2       = (const float*)d_in[18];
    const float* mw1       = (const float*)d_in[19];
    const float* mb1       = (const float*)d_in[20];
    const float* mw2       = (const float*)d_in[21];
    const float* mb2       = (const float*)d_in[22];
    const float* mw3       = (const float*)d_in[23];
    const float* mb3       = (const float*)d_in[24];
    float* out = (float*)d_out;

    // ---- workspace: [0,1MB) packed weights | [1MB,16MB) ints | [16MB,...) floats ----
    ushort* pw = (ushort*)d_ws;
    size_t off_w = 0;
    ushort *nwH, *nwL, *ewH, *ewL, *liH, *liL, *w1H, *w1L, *w2H, *w2L,
           *e1H, *e1L, *e2H, *e2L, *m1H, *m1L, *m2H, *m2L;
    auto nextw = [&](size_t s, ushort*& H, ushort*& L) { H = pw + off_w; L = pw + off_w + s; off_w += 2 * s; };
    nextw(128 * 128,     nwH, nwL);   // node_w  K=128
    nextw(128 * 64,      ewH, ewL);   // edge_w  K=64
    nextw(2 * 128 * 128, liH, liL);
    nextw(2 * 128 * 128, w1H, w1L);
    nextw(2 * 128 * 128, w2H, w2L);
    nextw(2 * 128 * 320, e1H, e1L);   // ew1 K=300
    nextw(2 * 128 * 128, e2H, e2L);
    nextw(64 * 320,      m1H, m1L);   // mw1 K=300 NCpad=64
    nextw(32 * 64,       m2H, m2L);   // mw2 K=50  NCpad=32

    int* intb = (int*)((char*)d_ws + (1u << 20));
    int* cnt  = intb;                  // N
    int* coff = cnt + N_NODES;         // N+1
    int* pos  = coff + N_NODES + 1;    // N
    int* eidx = pos + N_NODES;         // E
    int* psrc = eidx + N_EDGES;        // E
    int* pdst = psrc + N_EDGES;        // E

    float* fbase = (float*)((char*)d_ws + (16u << 20));
    float* e     = fbase;                                  // E*100 (CSR order)
    float* tmp   = e   + (size_t)N_EDGES * HDIM;           // E*100 (also z, f1)
    float* h     = tmp + (size_t)N_EDGES * HDIM;           // N*100
    float* agg   = h   + (size_t)N_NODES * HDIM;           // N*100
    float* stats = agg + (size_t)N_NODES * HDIM;           // 256
    float* z  = tmp;
    float* f1 = tmp;                                       // E*52

    const int* srcp = ei;
    const int* dstp = ei + N_EDGES;
    dim3 blk(256);

    // ---- pack weights ----
    auto packl = [&](const float* W, ushort* H, ushort* L, int K, int NC, int Kp, int NCp, int batch) {
        int total = batch * NCp * Kp;
        pack_k<<<(total + 255) / 256, blk, 0, stream>>>(W, H, L, K, NC, Kp, NCp, total);
    };
    packl(node_w, nwH, nwL, 128, 100, 128, 128, 1);
    packl(edge_w, ewH, ewL,  64, 100,  64, 128, 1);
    packl(lin_w,  liH, liL, 100, 100, 128, 128, 2);
    packl(w1,     w1H, w1L, 100, 100, 128, 128, 2);
    packl(w2,     w2H, w2L, 100, 100, 128, 128, 2);
    packl(ew1,    e1H, e1L, 300, 100, 320, 128, 2);
    packl(ew2,    e2H, e2L, 100, 100, 128, 128, 2);
    packl(mw1,    m1H, m1L, 300,  50, 320,  64, 1);
    packl(mw2,    m2H, m2L,  50,  25,  64,  32, 1);

    // ---- CSR build + edge permutation (once; graph static) ----
    hipMemsetAsync(cnt, 0, N_NODES * sizeof(int), stream);
    hist_k<<<(N_EDGES + 255) / 256, blk, 0, stream>>>(dstp, cnt);
    scan_k<<<1, dim3(1024), 0, stream>>>(cnt, coff);
    hipMemsetAsync(pos, 0, N_NODES * sizeof(int), stream);
    fill_k<<<(N_EDGES + 255) / 256, blk, 0, stream>>>(dstp, coff, pos, eidx);
    perm_k<<<(N_EDGES + 255) / 256, blk, 0, stream>>>(eidx, srcp, dstp, psrc, pdst);

    // 1. h = x @ node_w + node_b   K=128
    gemm6_k<8,2,4,0,0,3><<<gtile(N_NODES), blk, 0, stream>>>(
        x, nwH, nwL, node_b, h, N_NODES, 128, 128, 100, 100,
        nullptr, nullptr, nullptr, nullptr);
    // 2. e[j] = edge_attr[eidx[j]] @ edge_w + edge_b   K=64 (gather rows -> CSR order)
    gemm6_k<8,2,2,0,3,3><<<gtile(N_EDGES), blk, 0, stream>>>(
        edge_attr, ewH, ewL, edge_b, e, N_EDGES, 64, 64, 100, 100,
        eidx, nullptr, nullptr, nullptr);

    for (int i = 0; i < 2; ++i) {
        // 3. tmp = e @ lin_w[i] + lin_b[i]
        gemm6_k<8,2,4,0,0,3><<<gtile(N_EDGES), blk, 0, stream>>>(
            e, liH + (size_t)i * 16384, liL + (size_t)i * 16384, lin_b + i * HDIM, tmp,
            N_EDGES, 100, 100, 100, 100, nullptr, nullptr, nullptr, nullptr);
        // 4+5. agg = h + sum relu(h[src] + tmp)   (CSR-sequential)
        agg_k<<<(N_NODES * 25 + 255) / 256, blk, 0, stream>>>(h, tmp, psrc, coff, agg);
        // 6. z = relu(agg @ w1[i] + b1[i])
        gemm6_k<8,2,4,1,0,3><<<gtile(N_NODES), blk, 0, stream>>>(
            agg, w1H + (size_t)i * 16384, w1L + (size_t)i * 16384, b1 + i * HDIM, z,
            N_NODES, 100, 100, 100, 100, nullptr, nullptr, nullptr, nullptr);
        // 7. agg = z @ w2[i] + b2[i]
        gemm6_k<8,2,4,0,0,3><<<gtile(N_NODES), blk, 0, stream>>>(
            z, w2H + (size_t)i * 16384, w2L + (size_t)i * 16384, b2 + i * HDIM, agg,
            N_NODES, 100, 100, 100, 100, nullptr, nullptr, nullptr, nullptr);
        // 8. BN stats
        hipMemsetAsync(stats, 0, 2 * HDIM * sizeof(float), stream);
        bn_stats_k<<<1024, dim3(128), 0, stream>>>(agg, stats);
        // 9. h = (h + relu(BN(agg))) / 2
        bn_apply_k<<<(N_NODES * HDIM + 255) / 256, blk, 0, stream>>>(
            agg, stats, gamma + i * HDIM, beta + i * HDIM, h);
        // 10. tmp = relu(cat(h[src],h[dst],e) @ ew1[i] + eb1[i])   K=300
        gemm6_k<8,2,10,1,1,2><<<gtile(N_EDGES), blk, 0, stream>>>(
            nullptr, e1H + (size_t)i * 40960, e1L + (size_t)i * 40960, eb1 + i * HDIM, tmp,
            N_EDGES, 300, 0, 100, 100, psrc, pdst, h, e);
        // 11. e = e + 0.5*(tmp @ ew2[i] + eb2[i])
        gemm6_k<8,2,4,2,0,3><<<gtile(N_EDGES), blk, 0, stream>>>(
            tmp, e2H + (size_t)i * 16384, e2L + (size_t)i * 16384, eb2 + i * HDIM, e,
            N_EDGES, 100, 100, 100, 100, nullptr, nullptr, nullptr, nullptr);
    }

    // 12. f1 = relu(cat(relu(h[src]),relu(h[dst]),e) @ mw1 + mb1)   K=300, ldc=52
    gemm6_k<4,1,10,1,2,3><<<gtile(N_EDGES), blk, 0, stream>>>(
        nullptr, m1H, m1L, mb1, f1, N_EDGES, 300, 0, 50, 52, psrc, pdst, h, e);
    // 13+14. out[eidx[j]] = relu(f1 @ mw2 + mb2) @ mw3 + mb3   (fused, f2 never materialized)
    final_fused_k<<<gtile(N_EDGES), blk, 0, stream>>>(
        f1, m2H, m2L, mb2, mw3, mb3, eidx, out);
}

// Round 8
// 4316.941 us; speedup vs baseline: 1.4842x; 1.4842x over previous
//
#include <hip/hip_runtime.h>

#define N_NODES 100000
#define N_EDGES 800000
#define HDIM 100

typedef __attribute__((ext_vector_type(8))) short bf16x8;
typedef __attribute__((ext_vector_type(4))) float f32x4;

// ---------------- weight packing: W[batch][K][NC] fp32 -> transposed bf16 hi/lo [batch][NCpad][Kpad]
__global__ __launch_bounds__(256)
void pack_k(const float* __restrict__ W, ushort* __restrict__ hi, ushort* __restrict__ lo,
            int K, int NC, int Kpad, int NCpad, int total)
{
    int idx = blockIdx.x * 256 + threadIdx.x;
    if (idx >= total) return;
    int per = NCpad * Kpad;
    int b = idx / per, rem = idx - b * per;
    int col = rem / Kpad, k = rem - col * Kpad;
    float v = (col < NC && k < K) ? W[(long)b * K * NC + (long)k * NC + col] : 0.f;
    uint u = __float_as_uint(v);
    float r = v - __uint_as_float(u & 0xFFFF0000u);
    hi[idx] = (ushort)(u >> 16);
    lo[idx] = (ushort)(__float_as_uint(r) >> 16);
}

// ---------------- MFMA GEMM, T14 pipeline: issue loads early (regs), cvt+ds_write late.
// One 64-row tile per block. CH = K-chunks of 64 (Kpad = CH*64). TILES*16 = NCpad, TPW tiles/wave.
// MODE: 0 store, 1 relu, 2 C += 0.5*v. GATHER: 0 plain; 1 cat(h[g0],h[g1],e); 2 +relu on h segs; 3 rows via g0.
// Split precision: acc = aH*bH + aH*bL + aL*bH (fp32 accum), rel err ~2^-17.
// R8 fix: prefetch for chunk c+2 is issued AFTER MFMA(c) — the 2-slot B rotation
// means slot s holds chunk c's fragments during MFMA(c); issuing bload(c+2) into
// slot s before the MFMA (R7) overwrote them (WAR violation, wrong weights).
template<int TILES, int TPW, int CH, int MODE, int GATHER, int MINW>
__global__ __launch_bounds__(256, MINW)
void gemm7_k(const float* __restrict__ A,
             const ushort* __restrict__ wtH, const ushort* __restrict__ wtL,
             const float* __restrict__ bias, float* __restrict__ C,
             int M, int K, int lda, int NC, int ldc,
             const int* __restrict__ g0, const int* __restrict__ g1,
             const float* __restrict__ hbuf, const float* __restrict__ ebuf)
{
    constexpr int WAVES = TILES / TPW;
    constexpr int KPAD  = CH * 64;
    static_assert(WAVES * 64 == 256, "block must be 256 threads");
    __shared__ ushort AsH[2][64 * 64];   // 64 rows x 64 k bf16, 128B rows, XOR-swizzled
    __shared__ ushort AsL[2][64 * 64];
    __shared__ int sidx[64], didx[64];

    const int tid  = threadIdx.x;
    const int lane = tid & 63;
    const int w    = tid >> 6;
    const long row0 = (long)blockIdx.x * 64;

    if (GATHER == 1 || GATHER == 2) {
        if (tid < 64) {
            long gr = row0 + tid;
            sidx[tid] = (gr < M) ? g0[gr] : 0;
            didx[tid] = (gr < M) ? g1[gr] : 0;
        }
        __syncthreads();
    }

    // ---- issue A-loads for chunk ch into 4 float4 regs (no waits here) ----
    auto aload = [&](int ch, float4* va) {
#pragma unroll
        for (int it = 0; it < 4; ++it) {
            int idx = tid + it * 256;
            int r = idx >> 4, q = idx & 15;
            long grow = row0 + r;
            int gcol = ch * 64 + q * 4;
            float4 v = make_float4(0.f, 0.f, 0.f, 0.f);
            if (GATHER == 1 || GATHER == 2) {
                if (grow < M && gcol < K) {        // seg bounds (100,200) 4-aligned
                    int seg = (gcol >= 200) ? 2 : (gcol >= 100 ? 1 : 0);
                    int off = gcol - seg * 100;
                    long rr = (seg == 0) ? (long)sidx[r] : (seg == 1) ? (long)didx[r] : grow;
                    const float* base = (seg == 2) ? ebuf : hbuf;
                    v = *(const float4*)&base[rr * HDIM + off];
                    if (GATHER == 2 && seg < 2) {
                        v.x = fmaxf(v.x, 0.f); v.y = fmaxf(v.y, 0.f);
                        v.z = fmaxf(v.z, 0.f); v.w = fmaxf(v.w, 0.f);
                    }
                }
            } else if (GATHER == 3) {
                if (grow < M && gcol < K)
                    v = *(const float4*)&A[(long)g0[grow] * lda + gcol];
            } else {
                if (grow < M && gcol < K)
                    v = *(const float4*)&A[grow * (long)lda + gcol];
            }
            va[it] = v;
        }
    };

    // ---- issue B-frag loads for chunk ch (TPW tiles x 2 k-steps, hi+lo) ----
    auto bload = [&](int ch, bf16x8 (*bh)[2], bf16x8 (*bl)[2]) {
#pragma unroll
        for (int tp = 0; tp < TPW; ++tp) {
            int col = (w * TPW + tp) * 16 + (lane & 15);
#pragma unroll
            for (int ks = 0; ks < 2; ++ks) {
                long o = (long)col * KPAD + (ch * 2 + ks) * 32 + (lane >> 4) * 8;
                bh[tp][ks] = *(const bf16x8*)(wtH + o);
                bl[tp][ks] = *(const bf16x8*)(wtL + o);
            }
        }
    };

    // ---- cvt fp32->bf16 hi/lo and write chunk to LDS buffer s (waits on va only) ----
    auto cvtwrite = [&](const float4* va, int s) {
#pragma unroll
        for (int it = 0; it < 4; ++it) {
            int idx = tid + it * 256;
            int r = idx >> 4, q = idx & 15;
            float4 v = va[it];
            uint ux = __float_as_uint(v.x), uy = __float_as_uint(v.y);
            uint uz = __float_as_uint(v.z), uw = __float_as_uint(v.w);
            ushort4 hv = make_ushort4(ux >> 16, uy >> 16, uz >> 16, uw >> 16);
            float rx = v.x - __uint_as_float(ux & 0xFFFF0000u);
            float ry = v.y - __uint_as_float(uy & 0xFFFF0000u);
            float rz = v.z - __uint_as_float(uz & 0xFFFF0000u);
            float rw = v.w - __uint_as_float(uw & 0xFFFF0000u);
            ushort4 lv = make_ushort4(__float_as_uint(rx) >> 16, __float_as_uint(ry) >> 16,
                                      __float_as_uint(rz) >> 16, __float_as_uint(rw) >> 16);
            int boff = (r * 128 + q * 8) ^ ((r & 7) << 4);
            *(ushort4*)((char*)AsH[s] + boff) = hv;
            *(ushort4*)((char*)AsL[s] + boff) = lv;
        }
    };

    float4  va[2][4];
    bf16x8  bh[2][TPW][2], bl[2][TPW][2];
    f32x4   acc[TPW][4];
#pragma unroll
    for (int tp = 0; tp < TPW; ++tp)
#pragma unroll
        for (int rg = 0; rg < 4; ++rg) acc[tp][rg] = (f32x4){0.f, 0.f, 0.f, 0.f};

    // prologue: issue chunk0 (+chunk1) loads, stage chunk0
    aload(0, va[0]);
    bload(0, bh[0], bl[0]);
    if (CH > 1) { aload(1, va[1]); bload(1, bh[1], bl[1]); }
    cvtwrite(va[0], 0);
    __syncthreads();

#pragma unroll
    for (int c = 0; c < CH; ++c) {
        const int s = c & 1;
        // MFMA chunk c (LDS buf s + B slot s — both hold chunk c now)
#pragma unroll
        for (int ks = 0; ks < 2; ++ks) {
#pragma unroll
            for (int rg = 0; rg < 4; ++rg) {
                int arow = rg * 16 + (lane & 15);
                int aoff = (arow * 128 + ks * 64 + (lane >> 4) * 16) ^ ((arow & 7) << 4);
                bf16x8 aH = *(const bf16x8*)((const char*)AsH[s] + aoff);
                bf16x8 aL = *(const bf16x8*)((const char*)AsL[s] + aoff);
#pragma unroll
                for (int tp = 0; tp < TPW; ++tp) {
                    acc[tp][rg] = __builtin_amdgcn_mfma_f32_16x16x32_bf16(aH, bh[s][tp][ks], acc[tp][rg], 0, 0, 0);
                    acc[tp][rg] = __builtin_amdgcn_mfma_f32_16x16x32_bf16(aH, bl[s][tp][ks], acc[tp][rg], 0, 0, 0);
                    acc[tp][rg] = __builtin_amdgcn_mfma_f32_16x16x32_bf16(aL, bh[s][tp][ks], acc[tp][rg], 0, 0, 0);
                }
            }
        }
        // now slot s is free: issue loads for chunk c+2 (consumed at c+1's cvtwrite / c+2's MFMA)
        if (c + 2 < CH) {
            aload(c + 2, va[s]);
            bload(c + 2, bh[s], bl[s]);
        }
        // write chunk c+1 into the other buffer (its loads were issued a phase ago)
        if (c + 1 < CH) {
            cvtwrite(va[(c + 1) & 1], s ^ 1);
            __syncthreads();
        }
    }

    // ---- epilogue: C/D layout col=lane&15, row=(lane>>4)*4+i ----
#pragma unroll
    for (int tp = 0; tp < TPW; ++tp) {
        int col = (w * TPW + tp) * 16 + (lane & 15);
        if (col >= NC) continue;
        float bv = bias[col];
#pragma unroll
        for (int rg = 0; rg < 4; ++rg) {
#pragma unroll
            for (int i = 0; i < 4; ++i) {
                long grow = row0 + rg * 16 + (lane >> 4) * 4 + i;
                if (grow >= M) continue;
                float v = acc[tp][rg][i] + bv;
                if (MODE == 1) v = fmaxf(v, 0.f);
                long o = grow * (long)ldc + col;
                if (MODE == 2) C[o] += 0.5f * v;
                else           C[o] = v;
            }
        }
    }
}

// ---------------- fused final: out = relu(f1 @ mw2 + mb2) @ mw3 + mb3, scattered to original order
__global__ __launch_bounds__(256, 2)
void final_fused_k(const float* __restrict__ f1,   // [E][52] permuted, cols 50-51 garbage
                   const ushort* __restrict__ m2H, const ushort* __restrict__ m2L, // NCpad=32, Kpad=64
                   const float* __restrict__ mb2, const float* __restrict__ mw3,
                   const float* __restrict__ mb3,
                   const int* __restrict__ eidx, float* __restrict__ out)
{
    __shared__ ushort AsH[2][64 * 64];
    __shared__ ushort AsL[2][64 * 64];
    const int tid = threadIdx.x, lane = tid & 63, w = tid >> 6;
    const int c = lane & 15;
    const int ntiles = N_EDGES / 64;
    const int ltiles = (ntiles - blockIdx.x + gridDim.x - 1) / gridDim.x;

    bf16x8 bH[2][2], bL[2][2];
#pragma unroll
    for (int t = 0; t < 2; ++t)
#pragma unroll
        for (int ks = 0; ks < 2; ++ks) {
            long o = (long)(t * 16 + c) * 64 + ks * 32 + (lane >> 4) * 8;
            bH[t][ks] = *(const bf16x8*)(m2H + o);
            bL[t][ks] = *(const bf16x8*)(m2L + o);
        }
    const float bias0 = mb2[c];
    const float bias1 = (c + 16 < 25) ? mb2[c + 16] : 0.f;
    const float w3a0 = mw3[c * 2 + 0], w3a1 = mw3[c * 2 + 1];
    const float w3b0 = (c + 16 < 25) ? mw3[(c + 16) * 2 + 0] : 0.f;
    const float w3b1 = (c + 16 < 25) ? mw3[(c + 16) * 2 + 1] : 0.f;
    const float b30 = mb3[0], b31 = mb3[1];

    auto aload = [&](int tl, float4* va) {
        long row0 = (blockIdx.x + (long)tl * gridDim.x) * 64;
#pragma unroll
        for (int it = 0; it < 4; ++it) {
            int idx = tid + it * 256;
            int r = idx >> 4, q = idx & 15;
            float4 v = make_float4(0.f, 0.f, 0.f, 0.f);
            if (q < 13) {
                v = *(const float4*)&f1[(row0 + r) * 52 + q * 4];
                if (q == 12) { v.z = 0.f; v.w = 0.f; }
            }
            va[it] = v;
        }
    };
    auto cvtwrite = [&](const float4* va, int s) {
#pragma unroll
        for (int it = 0; it < 4; ++it) {
            int idx = tid + it * 256;
            int r = idx >> 4, q = idx & 15;
            float4 v = va[it];
            uint ux = __float_as_uint(v.x), uy = __float_as_uint(v.y);
            uint uz = __float_as_uint(v.z), uw = __float_as_uint(v.w);
            ushort4 hv = make_ushort4(ux >> 16, uy >> 16, uz >> 16, uw >> 16);
            float rx = v.x - __uint_as_float(ux & 0xFFFF0000u);
            float ry = v.y - __uint_as_float(uy & 0xFFFF0000u);
            float rz = v.z - __uint_as_float(uz & 0xFFFF0000u);
            float rw = v.w - __uint_as_float(uw & 0xFFFF0000u);
            ushort4 lv = make_ushort4(__float_as_uint(rx) >> 16, __float_as_uint(ry) >> 16,
                                      __float_as_uint(rz) >> 16, __float_as_uint(rw) >> 16);
            int boff = (r * 128 + q * 8) ^ ((r & 7) << 4);
            *(ushort4*)((char*)AsH[s] + boff) = hv;
            *(ushort4*)((char*)AsL[s] + boff) = lv;
        }
    };

    float4 va[2][4];
    aload(0, va[0]);
    if (ltiles > 1) aload(1, va[1]);
    cvtwrite(va[0], 0);
    __syncthreads();

    for (int tl = 0; tl < ltiles; ++tl) {
        const int s = tl & 1;
        f32x4 a0 = (f32x4){0.f, 0.f, 0.f, 0.f}, a1 = a0;
        const int arow = w * 16 + c;
#pragma unroll
        for (int ks = 0; ks < 2; ++ks) {
            int aoff = (arow * 128 + ks * 64 + (lane >> 4) * 16) ^ ((arow & 7) << 4);
            bf16x8 aH = *(const bf16x8*)((const char*)AsH[s] + aoff);
            bf16x8 aL = *(const bf16x8*)((const char*)AsL[s] + aoff);
            a0 = __builtin_amdgcn_mfma_f32_16x16x32_bf16(aH, bH[0][ks], a0, 0, 0, 0);
            a0 = __builtin_amdgcn_mfma_f32_16x16x32_bf16(aH, bL[0][ks], a0, 0, 0, 0);
            a0 = __builtin_amdgcn_mfma_f32_16x16x32_bf16(aL, bH[0][ks], a0, 0, 0, 0);
            a1 = __builtin_amdgcn_mfma_f32_16x16x32_bf16(aH, bH[1][ks], a1, 0, 0, 0);
            a1 = __builtin_amdgcn_mfma_f32_16x16x32_bf16(aH, bL[1][ks], a1, 0, 0, 0);
            a1 = __builtin_amdgcn_mfma_f32_16x16x32_bf16(aL, bH[1][ks], a1, 0, 0, 0);
        }
        if (tl + 2 < ltiles) aload(tl + 2, va[s]);
        long row0 = (blockIdx.x + (long)tl * gridDim.x) * 64;
#pragma unroll
        for (int i = 0; i < 4; ++i) {
            float t0 = fmaxf(a0[i] + bias0, 0.f);
            float t1 = fmaxf(a1[i] + bias1, 0.f);
            float s0 = t0 * w3a0 + t1 * w3b0;
            float s1 = t0 * w3a1 + t1 * w3b1;
#pragma unroll
            for (int d = 1; d < 16; d <<= 1) {
                s0 += __shfl_xor(s0, d, 64);
                s1 += __shfl_xor(s1, d, 64);
            }
            if (c == 0) {
                long grow = row0 + w * 16 + (lane >> 4) * 4 + i;
                int oe = eidx[grow];
                out[(long)oe * 2 + 0] = s0 + b30;
                out[(long)oe * 2 + 1] = s1 + b31;
            }
        }
        if (tl + 1 < ltiles) {
            cvtwrite(va[(tl + 1) & 1], s ^ 1);
            __syncthreads();
        }
    }
}

// ---------------- CSR build ----------------
__global__ __launch_bounds__(256)
void hist_k(const int* __restrict__ dst, int* __restrict__ cnt)
{
    int e = blockIdx.x * 256 + threadIdx.x;
    if (e < N_EDGES) atomicAdd(&cnt[dst[e]], 1);
}

__global__ __launch_bounds__(1024)
void scan_k(const int* __restrict__ cnt, int* __restrict__ off)
{
    __shared__ int part[1024];
    const int t = threadIdx.x;
    const int per = (N_NODES + 1023) / 1024;
    const int base = t * per;
    int s = 0;
    for (int i = 0; i < per; ++i) {
        int n = base + i;
        if (n < N_NODES) s += cnt[n];
    }
    part[t] = s;
    __syncthreads();
    for (int d = 1; d < 1024; d <<= 1) {
        int v = (t >= d) ? part[t - d] : 0;
        __syncthreads();
        part[t] += v;
        __syncthreads();
    }
    int run = (t == 0) ? 0 : part[t - 1];
    for (int i = 0; i < per; ++i) {
        int n = base + i;
        if (n < N_NODES) { off[n] = run; run += cnt[n]; }
    }
    if (t == 1023) off[N_NODES] = run;
}

__global__ __launch_bounds__(256)
void fill_k(const int* __restrict__ dst, const int* __restrict__ off,
            int* __restrict__ pos, int* __restrict__ eidx)
{
    int e = blockIdx.x * 256 + threadIdx.x;
    if (e >= N_EDGES) return;
    int d = dst[e];
    int p = atomicAdd(&pos[d], 1);
    eidx[off[d] + p] = e;
}

__global__ __launch_bounds__(256)
void perm_k(const int* __restrict__ eidx, const int* __restrict__ src,
            const int* __restrict__ dst, int* __restrict__ psrc, int* __restrict__ pdst)
{
    int j = blockIdx.x * 256 + threadIdx.x;
    if (j >= N_EDGES) return;
    int e = eidx[j];
    psrc[j] = src[e];
    pdst[j] = dst[e];
}

// ---------------- aggregation (CSR-sequential): agg[n] = h[n] + sum_j relu(h[psrc[j]] + tmp[j])
__global__ __launch_bounds__(256)
void agg_k(const float* __restrict__ h, const float* __restrict__ tmp,
           const int* __restrict__ psrc, const int* __restrict__ off,
           float* __restrict__ agg)
{
    unsigned idx = blockIdx.x * 256u + threadIdx.x;
    if (idx >= (unsigned)(N_NODES * 25)) return;
    unsigned n = idx / 25u;
    unsigned q = (idx - n * 25u) * 4u;
    float4 a = *(const float4*)&h[(long)n * HDIM + q];
    int j0 = off[n], j1 = off[n + 1];
    for (int j = j0; j < j1; ++j) {
        int s = psrc[j];
        float4 t  = *(const float4*)&tmp[(long)j * HDIM + q];
        float4 hv = *(const float4*)&h[(long)s * HDIM + q];
        a.x += fmaxf(hv.x + t.x, 0.f);
        a.y += fmaxf(hv.y + t.y, 0.f);
        a.z += fmaxf(hv.z + t.z, 0.f);
        a.w += fmaxf(hv.w + t.w, 0.f);
    }
    *(float4*)&agg[(long)n * HDIM + q] = a;
}

__global__ __launch_bounds__(128)
void bn_stats_k(const float* __restrict__ z, float* __restrict__ stats)
{
    int c = threadIdx.x;
    if (c >= HDIM) return;
    long rows_per = (N_NODES + gridDim.x - 1) / gridDim.x;
    long r0 = (long)blockIdx.x * rows_per;
    long r1 = r0 + rows_per; if (r1 > N_NODES) r1 = N_NODES;
    float s = 0.f, s2 = 0.f;
    for (long r = r0; r < r1; ++r) {
        float v = z[r * HDIM + c];
        s += v; s2 += v * v;
    }
    atomicAdd(&stats[c], s);
    atomicAdd(&stats[HDIM + c], s2);
}

__global__ __launch_bounds__(256)
void bn_apply_k(const float* __restrict__ z, const float* __restrict__ stats,
                const float* __restrict__ gamma, const float* __restrict__ beta,
                float* __restrict__ h)
{
    unsigned idx = blockIdx.x * 256u + threadIdx.x;
    if (idx >= (unsigned)(N_NODES * HDIM)) return;
    unsigned c = idx % HDIM;
    const float invN = 1.f / N_NODES;
    float mu  = stats[c] * invN;
    float var = stats[HDIM + c] * invN - mu * mu;
    float v = (z[idx] - mu) * rsqrtf(var + 1e-5f) * gamma[c] + beta[c];
    h[idx] = (h[idx] + fmaxf(v, 0.f)) * 0.5f;
}

static inline int gb64(long m) { return (int)((m + 63) / 64); }

extern "C" void kernel_launch(void* const* d_in, const int* in_sizes, int n_in,
                              void* d_out, int out_size, void* d_ws, size_t ws_size,
                              hipStream_t stream)
{
    const float* x         = (const float*)d_in[0];
    const int*   ei        = (const int*)  d_in[1];
    const float* edge_attr = (const float*)d_in[2];
    const float* node_w    = (const float*)d_in[3];
    const float* node_b    = (const float*)d_in[4];
    const float* edge_w    = (const float*)d_in[5];
    const float* edge_b    = (const float*)d_in[6];
    const float* lin_w     = (const float*)d_in[7];
    const float* lin_b     = (const float*)d_in[8];
    const float* w1        = (const float*)d_in[9];
    const float* b1        = (const float*)d_in[10];
    const float* w2        = (const float*)d_in[11];
    const float* b2        = (const float*)d_in[12];
    const float* gamma     = (const float*)d_in[13];
    const float* beta      = (const float*)d_in[14];
    const float* ew1       = (const float*)d_in[15];
    const float* eb1       = (const float*)d_in[16];
    const float* ew2       = (const float*)d_in[17];
    const float* eb2       = (const float*)d_in[18];
    const float* mw1       = (const float*)d_in[19];
    const float* mb1       = (const float*)d_in[20];
    const float* mw2       = (const float*)d_in[21];
    const float* mb2       = (const float*)d_in[22];
    const float* mw3       = (const float*)d_in[23];
    const float* mb3       = (const float*)d_in[24];
    float* out = (float*)d_out;

    // ---- workspace: [0,1MB) packed weights | [1MB,16MB) ints | [16MB,...) floats ----
    ushort* pw = (ushort*)d_ws;
    size_t off_w = 0;
    ushort *nwH, *nwL, *ewH, *ewL, *liH, *liL, *w1H, *w1L, *w2H, *w2L,
           *e1H, *e1L, *e2H, *e2L, *m1H, *m1L, *m2H, *m2L;
    auto nextw = [&](size_t s, ushort*& H, ushort*& L) { H = pw + off_w; L = pw + off_w + s; off_w += 2 * s; };
    nextw(128 * 128,     nwH, nwL);   // node_w  K=128
    nextw(128 * 64,      ewH, ewL);   // edge_w  K=64
    nextw(2 * 128 * 128, liH, liL);
    nextw(2 * 128 * 128, w1H, w1L);
    nextw(2 * 128 * 128, w2H, w2L);
    nextw(2 * 128 * 320, e1H, e1L);   // ew1 K=300
    nextw(2 * 128 * 128, e2H, e2L);
    nextw(64 * 320,      m1H, m1L);   // mw1 K=300 NCpad=64
    nextw(32 * 64,       m2H, m2L);   // mw2 K=50  NCpad=32

    int* intb = (int*)((char*)d_ws + (1u << 20));
    int* cnt  = intb;                  // N
    int* coff = cnt + N_NODES;         // N+1
    int* pos  = coff + N_NODES + 1;    // N
    int* eidx = pos + N_NODES;         // E
    int* psrc = eidx + N_EDGES;        // E
    int* pdst = psrc + N_EDGES;        // E

    float* fbase = (float*)((char*)d_ws + (16u << 20));
    float* e     = fbase;                                  // E*100 (CSR order)
    float* tmp   = e   + (size_t)N_EDGES * HDIM;           // E*100 (also z, f1)
    float* h     = tmp + (size_t)N_EDGES * HDIM;           // N*100
    float* agg   = h   + (size_t)N_NODES * HDIM;           // N*100
    float* stats = agg + (size_t)N_NODES * HDIM;           // 256
    float* z  = tmp;
    float* f1 = tmp;                                       // E*52

    const int* srcp = ei;
    const int* dstp = ei + N_EDGES;
    dim3 blk(256);

    // ---- pack weights ----
    auto packl = [&](const float* W, ushort* H, ushort* L, int K, int NC, int Kp, int NCp, int batch) {
        int total = batch * NCp * Kp;
        pack_k<<<(total + 255) / 256, blk, 0, stream>>>(W, H, L, K, NC, Kp, NCp, total);
    };
    packl(node_w, nwH, nwL, 128, 100, 128, 128, 1);
    packl(edge_w, ewH, ewL,  64, 100,  64, 128, 1);
    packl(lin_w,  liH, liL, 100, 100, 128, 128, 2);
    packl(w1,     w1H, w1L, 100, 100, 128, 128, 2);
    packl(w2,     w2H, w2L, 100, 100, 128, 128, 2);
    packl(ew1,    e1H, e1L, 300, 100, 320, 128, 2);
    packl(ew2,    e2H, e2L, 100, 100, 128, 128, 2);
    packl(mw1,    m1H, m1L, 300,  50, 320,  64, 1);
    packl(mw2,    m2H, m2L,  50,  25,  64,  32, 1);

    // ---- CSR build + edge permutation (once; graph static) ----
    hipMemsetAsync(cnt, 0, N_NODES * sizeof(int), stream);
    hist_k<<<(N_EDGES + 255) / 256, blk, 0, stream>>>(dstp, cnt);
    scan_k<<<1, dim3(1024), 0, stream>>>(cnt, coff);
    hipMemsetAsync(pos, 0, N_NODES * sizeof(int), stream);
    fill_k<<<(N_EDGES + 255) / 256, blk, 0, stream>>>(dstp, coff, pos, eidx);
    perm_k<<<(N_EDGES + 255) / 256, blk, 0, stream>>>(eidx, srcp, dstp, psrc, pdst);

    // 1. h = x @ node_w + node_b   K=128, CH=2
    gemm7_k<8,2,2,0,0,2><<<gb64(N_NODES), blk, 0, stream>>>(
        x, nwH, nwL, node_b, h, N_NODES, 128, 128, 100, 100,
        nullptr, nullptr, nullptr, nullptr);
    // 2. e[j] = edge_attr[eidx[j]] @ edge_w + edge_b   K=64, CH=1
    gemm7_k<8,2,1,0,3,2><<<gb64(N_EDGES), blk, 0, stream>>>(
        edge_attr, ewH, ewL, edge_b, e, N_EDGES, 64, 64, 100, 100,
        eidx, nullptr, nullptr, nullptr);

    for (int i = 0; i < 2; ++i) {
        // 3. tmp = e @ lin_w[i] + lin_b[i]   K=100, CH=2
        gemm7_k<8,2,2,0,0,2><<<gb64(N_EDGES), blk, 0, stream>>>(
            e, liH + (size_t)i * 16384, liL + (size_t)i * 16384, lin_b + i * HDIM, tmp,
            N_EDGES, 100, 100, 100, 100, nullptr, nullptr, nullptr, nullptr);
        // 4+5. agg = h + sum relu(h[src] + tmp)   (CSR-sequential)
        agg_k<<<(N_NODES * 25 + 255) / 256, blk, 0, stream>>>(h, tmp, psrc, coff, agg);
        // 6. z = relu(agg @ w1[i] + b1[i])
        gemm7_k<8,2,2,1,0,2><<<gb64(N_NODES), blk, 0, stream>>>(
            agg, w1H + (size_t)i * 16384, w1L + (size_t)i * 16384, b1 + i * HDIM, z,
            N_NODES, 100, 100, 100, 100, nullptr, nullptr, nullptr, nullptr);
        // 7. agg = z @ w2[i] + b2[i]
        gemm7_k<8,2,2,0,0,2><<<gb64(N_NODES), blk, 0, stream>>>(
            z, w2H + (size_t)i * 16384, w2L + (size_t)i * 16384, b2 + i * HDIM, agg,
            N_NODES, 100, 100, 100, 100, nullptr, nullptr, nullptr, nullptr);
        // 8. BN stats
        hipMemsetAsync(stats, 0, 2 * HDIM * sizeof(float), stream);
        bn_stats_k<<<1024, dim3(128), 0, stream>>>(agg, stats);
        // 9. h = (h + relu(BN(agg))) / 2
        bn_apply_k<<<(N_NODES * HDIM + 255) / 256, blk, 0, stream>>>(
            agg, stats, gamma + i * HDIM, beta + i * HDIM, h);
        // 10. tmp = relu(cat(h[src],h[dst],e) @ ew1[i] + eb1[i])   K=300, CH=5
        gemm7_k<8,2,5,1,1,2><<<gb64(N_EDGES), blk, 0, stream>>>(
            nullptr, e1H + (size_t)i * 40960, e1L + (size_t)i * 40960, eb1 + i * HDIM, tmp,
            N_EDGES, 300, 0, 100, 100, psrc, pdst, h, e);
        // 11. e = e + 0.5*(tmp @ ew2[i] + eb2[i])
        gemm7_k<8,2,2,2,0,2><<<gb64(N_EDGES), blk, 0, stream>>>(
            tmp, e2H + (size_t)i * 16384, e2L + (size_t)i * 16384, eb2 + i * HDIM, e,
            N_EDGES, 100, 100, 100, 100, nullptr, nullptr, nullptr, nullptr);
    }

    // 12. f1 = relu(cat(relu(h[src]),relu(h[dst]),e) @ mw1 + mb1)   K=300, CH=5, ldc=52
    gemm7_k<4,1,5,1,2,2><<<gb64(N_EDGES), blk, 0, stream>>>(
        nullptr, m1H, m1L, mb1, f1, N_EDGES, 300, 0, 50, 52, psrc, pdst, h, e);
    // 13+14. out[eidx[j]] = relu(f1 @ mw2 + mb2) @ mw3 + mb3   (fused)
    final_fused_k<<<1024, blk, 0, stream>>>(
        f1, m2H, m2L, mb2, mw3, mb3, eidx, out);
}